// Round 6
// baseline (888.353 us; speedup 1.0000x reference)
//
#include <hip/hip_runtime.h>
#include <hip/hip_bf16.h>

#define BB 512
#define TT 512
#define HH 100
#define DI 101
#define DOUT 2
#define BT (BB * TT)

typedef float f4 __attribute__((ext_vector_type(4)));

// ---------------------------------------------------------------------------
// Kernel 0 (prep): pack Wx [100][101] into 16B-aligned padded WxP [100][104].
// ---------------------------------------------------------------------------
__global__ void k_prep(const float* __restrict__ Wx, float* __restrict__ WxP) {
  const int t = threadIdx.x;
  for (int idx = t; idx < HH * 104; idx += 256) {
    const int r = idx / 104;
    const int c = idx - r * 104;
    WxP[idx] = (c < DI) ? Wx[r * DI + c] : 0.f;
  }
}

// ---------------------------------------------------------------------------
// Kernel 1: xp[r, c] = dot(in[r, :101], Wx[c, :101]) + b[c]
// ROUND-5 DIAGNOSIS: this kernel sat at ~290us through SIX rounds because
// the 26 weight quads/thread were never register-resident — they were
// re-fetched from L2 every row iteration: 4096 blocks x 2 waves x 64 rows
// x 26 KB ~= 13.6 TB -> ~290us AT THE L2 BW CEILING (~35 TB/s). Staging and
// shuffle fixes never touched the real bottleneck.
// FIX: weights live in AGPRs ("a" constraint, gfx950 unified file), with an
// empty asm "+a" touch INSIDE the row loop right before each use: the
// in-loop redefinition (a) pins the value in an AGPR at every iteration (no
// scratch spill), (b) makes any a->v copy un-hoistable (no LICM pressure).
// New floor: LDS broadcast-return BW (~133us for 1664 b128/block).
// ---------------------------------------------------------------------------
__global__ __launch_bounds__(128, 2) void k_inproj(
    const float* __restrict__ in, const float* __restrict__ WxP,
    const float* __restrict__ bias, float* __restrict__ xp) {
  const int t = threadIdx.x;
  const int p = t >> 1;    // pair id 0..63
  const int kh = t & 1;    // k half
  const int c0 = p;        // always < 100
  const int c1 = p + 64;
  const bool c1ok = (c1 < HH);

  __shared__ __align__(16) float Atile[64 * 104];

  // --- W fragments: aligned float4 from padded WxP -> AGPR home ---
  f4 wx0[13], wx1[13];
  {
    const f4* w0p = (const f4*)(WxP + (size_t)c0 * 104 + kh * 52);
    const f4* w1p = (const f4*)(WxP + (size_t)(c1ok ? c1 : 0) * 104 + kh * 52);
#pragma unroll
    for (int j = 0; j < 13; ++j) {
      wx0[j] = w0p[j];
      wx1[j] = w1p[j];
      asm volatile("" : "+a"(wx0[j]), "+a"(wx1[j]));  // establish AGPR home
    }
  }
  const float bs0 = bias[c0];
  const float bs1 = c1ok ? bias[c1] : 0.f;

  const int row0 = blockIdx.x * 64;

  // --- coalesced staging: 1616 quads, thread t takes quads j*128+t ---
  {
    const f4* src = (const f4*)(in + (size_t)row0 * DI);  // 16B-aligned
#pragma unroll
    for (int j = 0; j < 13; ++j) {
      const int Q = j * 128 + t;
      if (Q < 1616) {
        f4 v = src[Q];
        const int m = 4 * Q;  // flat dword index = r*101 + c
#pragma unroll
        for (int kcomp = 0; kcomp < 4; ++kcomp) {
          const int mi = m + kcomp;
          const int r = mi / 101;          // magic-mul
          const int c = mi - r * 101;
          Atile[r * 104 + c] = v[kcomp];
        }
      }
    }
    // zero pads (cols 101..103) so odd-half b128 reads see zeros
    if (t < 64) {
      Atile[t * 104 + 101] = 0.f;
      Atile[t * 104 + 102] = 0.f;
      Atile[t * 104 + 103] = 0.f;
    }
  }
  __syncthreads();

  // --- compute: every thread walks all 64 rows, 2 cols each ---
#pragma unroll 2
  for (int r = 0; r < 64; ++r) {
    const f4* a4 = (const f4*)(Atile + r * 104 + kh * 52);
    f4 s0 = {0.f, 0.f, 0.f, 0.f};
    f4 s1 = {0.f, 0.f, 0.f, 0.f};
#pragma unroll
    for (int j = 0; j < 13; ++j) {
      asm volatile("" : "+a"(wx0[j]), "+a"(wx1[j]));  // in-loop AGPR touch
      f4 av = a4[j];
      s0 = __builtin_elementwise_fma(av, wx0[j], s0);
      s1 = __builtin_elementwise_fma(av, wx1[j], s1);
    }
    float p0 = (s0.x + s0.y) + (s0.z + s0.w);
    float p1 = (s1.x + s1.y) + (s1.z + s1.w);
    // pair-reduce on the VALU pipe: quad_perm [1,0,3,2] swaps lane^1
    p0 += __int_as_float(__builtin_amdgcn_mov_dpp(
        __float_as_int(p0), 0xB1, 0xF, 0xF, true));
    p1 += __int_as_float(__builtin_amdgcn_mov_dpp(
        __float_as_int(p1), 0xB1, 0xF, 0xF, true));
    if (kh == 0) {
      float* xr = xp + (size_t)(row0 + r) * HH;
      xr[c0] = p0 + bs0;
      if (c1ok) xr[c1] = p1 + bs1;
    }
  }
}

// ---------------------------------------------------------------------------
// Kernel 2: barrier-free scan, one wave per batch.
// ROUND-5 DIAGNOSIS (closes the model at last): rounds 0-5 were ALL
// L2-BW-bound on per-step weight re-fetch. VGPR_Count never exceeded 132:
// the 200 dwords of Wh rows were re-read from L2/scratch EVERY step —
// 512 waves x 51KB x 512 steps = 13.4 TB / 348us = 38 TB/s == the L2
// ceiling (m56: 36.9). VALUBusy 18% (~300cy real work of a 1630cy step)
// corroborates. "+v" pins failed because the allocator spilled the asm
// results right back to scratch.
// FIX: weights in AGPRs (unified file, 'a' constraint) with empty-asm
// "+a" touches INSIDE the step loop before each use — pinned at every
// iteration, copies un-hoistable. 200 AGPR + ~128 VGPR fits 1 wave/EU.
// Predicted step: max(VALU ~550cy, LDS 25x12cy) -> ~120-150us.
// ---------------------------------------------------------------------------
__global__ __launch_bounds__(64, 1) void k_scan(
    const float* __restrict__ noise, const float* __restrict__ Wh,
    const float* __restrict__ ah0, float* hstore /* aliases xp staging */) {
  const int b = blockIdx.x;
  const int l = threadIdx.x;   // 0..63
  const bool act = (l < 50);
  const int s0 = act ? 2 * l : 0;  // clamped state-pair base

  __shared__ __align__(16) float h_lds[HH];  // 100 floats = 25 float4

  // --- weights: rows s0, s0+1 -> AGPR home ---
  f4 w0[25], w1[25];
  {
    const f4* r0 = (const f4*)(Wh + (size_t)s0 * HH);
    const f4* r1 = (const f4*)(Wh + (size_t)(s0 + 1) * HH);
#pragma unroll
    for (int j = 0; j < 25; ++j) {
      w0[j] = r0[j];
      w1[j] = r1[j];
      asm volatile("" : "+a"(w0[j]), "+a"(w1[j]));  // establish AGPR home
    }
  }

  float ahx = 0.f, ahy = 0.f;
  if (act) {
    float2 a = *(const float2*)(ah0 + s0);
    ahx = a.x; ahy = a.y;
  }
  // initial h = retanh(ah0), no noise
  {
    float e0 = __expf(-2.f * ahx);
    float e1 = __expf(-2.f * ahy);
    float h0 = (ahx > 0.f) ? (1.f - e0) * __builtin_amdgcn_rcpf(1.f + e0) : 0.f;
    float h1 = (ahy > 0.f) ? (1.f - e1) * __builtin_amdgcn_rcpf(1.f + e1) : 0.f;
    if (act) *(float2*)&h_lds[s0] = make_float2(h0, h1);
  }

  const float* xp_base = hstore;  // in-place staging from k_inproj
  const size_t bbase = (size_t)b * TT * HH;

  // 4-deep prefetch
  float2 xpA = make_float2(0.f, 0.f), nzA = xpA;
  float2 xpB = xpA, nzB = xpA, xpC = xpA, nzC = xpA, xpD = xpA, nzD = xpA;
  if (act) {
    xpA = *(const float2*)(xp_base + bbase + (size_t)0 * HH + s0);
    nzA = *(const float2*)(noise + bbase + (size_t)0 * HH + s0);
    xpB = *(const float2*)(xp_base + bbase + (size_t)1 * HH + s0);
    nzB = *(const float2*)(noise + bbase + (size_t)1 * HH + s0);
    xpC = *(const float2*)(xp_base + bbase + (size_t)2 * HH + s0);
    nzC = *(const float2*)(noise + bbase + (size_t)2 * HH + s0);
    xpD = *(const float2*)(xp_base + bbase + (size_t)3 * HH + s0);
    nzD = *(const float2*)(noise + bbase + (size_t)3 * HH + s0);
  }

#define STEP(XP, NZ, tc)                                                      \
  {                                                                           \
    const int tpf = (tc) + 4;                                                 \
    float2 nxp = make_float2(0.f, 0.f), nnz = nxp;                            \
    if (act && tpf < TT) {                                                    \
      nxp = *(const float2*)(xp_base + bbase + (size_t)tpf * HH + s0);        \
      nnz = *(const float2*)(noise + bbase + (size_t)tpf * HH + s0);          \
    }                                                                         \
    const f4* h4 = (const f4*)h_lds;                                          \
    f4 a0e = {0.f, 0.f, 0.f, 0.f}, a0o = a0e;                                 \
    f4 a1e = a0e, a1o = a0e;                                                  \
    _Pragma("unroll") for (int j = 0; j < 24; j += 2) {                       \
      asm volatile("" : "+a"(w0[j]), "+a"(w1[j]));     /* in-loop touch */    \
      asm volatile("" : "+a"(w0[j + 1]), "+a"(w1[j + 1]));                    \
      f4 hvE = h4[j];     /* uniform-address broadcast read */                \
      f4 hvO = h4[j + 1];                                                     \
      a0e = __builtin_elementwise_fma(w0[j], hvE, a0e);                       \
      a1e = __builtin_elementwise_fma(w1[j], hvE, a1e);                       \
      a0o = __builtin_elementwise_fma(w0[j + 1], hvO, a0o);                   \
      a1o = __builtin_elementwise_fma(w1[j + 1], hvO, a1o);                   \
    }                                                                         \
    {                                                                         \
      asm volatile("" : "+a"(w0[24]), "+a"(w1[24]));                          \
      f4 hvL = h4[24];                                                        \
      a0e = __builtin_elementwise_fma(w0[24], hvL, a0e);                      \
      a1e = __builtin_elementwise_fma(w1[24], hvL, a1e);                      \
    }                                                                         \
    f4 acc0 = a0e + a0o;                                                      \
    f4 acc1 = a1e + a1o;                                                      \
    float d0 = (acc0.x + acc0.y) + (acc0.z + acc0.w);                         \
    float d1 = (acc1.x + acc1.y) + (acc1.z + acc1.w);                         \
    ahx = fmaf(0.1f, (d0 + XP.x) - ahx, ahx);                                 \
    ahy = fmaf(0.1f, (d1 + XP.y) - ahy, ahy);                                 \
    float e0 = __expf(-2.f * ahx);                                            \
    float e1 = __expf(-2.f * ahy);                                            \
    float h0 = (ahx > 0.f) ? (1.f - e0) * __builtin_amdgcn_rcpf(1.f + e0)     \
                           : 0.f;                                             \
    float h1 = (ahy > 0.f) ? (1.f - e1) * __builtin_amdgcn_rcpf(1.f + e1)     \
                           : 0.f;                                             \
    h0 += NZ.x;                                                               \
    h1 += NZ.y;                                                               \
    /* all h4 reads above precede this write in wave program order */         \
    if (act) {                                                                \
      *(float2*)&h_lds[s0] = make_float2(h0, h1);                             \
      *(float2*)(hstore + bbase + (size_t)(tc)*HH + s0) =                     \
          make_float2(h0, h1);                                                \
    }                                                                         \
    XP = nxp;                                                                 \
    NZ = nnz;                                                                 \
  }

#pragma unroll 1
  for (int tc = 0; tc < TT; tc += 4) {
    STEP(xpA, nzA, tc);
    STEP(xpB, nzB, tc + 1);
    STEP(xpC, nzC, tc + 2);
    STEP(xpD, nzD, tc + 3);
  }
#undef STEP
}

// ---------------------------------------------------------------------------
// Kernel 3: out[r, 0:2] = hstore[r, :] @ Wy^T.  Memory-bound stream of
// hstore (105 MB), ~25-40us. Unchanged.
// ---------------------------------------------------------------------------
__global__ __launch_bounds__(256, 2) void k_outproj(
    const float* __restrict__ hstore, const float* __restrict__ Wy,
    float* __restrict__ out) {
  __shared__ __align__(16) float wy_l[2][HH];
  const int t = threadIdx.x;
  if (t < 2 * HH) {
    int r = t / HH;
    int c = t - r * HH;
    wy_l[r][c] = Wy[t];
  }
  __syncthreads();

  const int row = blockIdx.x * 256 + t;
  const float4* h4 = (const float4*)(hstore + (size_t)row * HH);
  const float4* w0 = (const float4*)wy_l[0];
  const float4* w1 = (const float4*)wy_l[1];
  float4 a0 = make_float4(0.f, 0.f, 0.f, 0.f);
  float4 a1 = make_float4(0.f, 0.f, 0.f, 0.f);
#pragma unroll
  for (int j = 0; j < 25; ++j) {
    float4 hv = h4[j];
    float4 x0 = w0[j];
    float4 x1 = w1[j];
    a0.x = fmaf(hv.x, x0.x, a0.x);
    a0.y = fmaf(hv.y, x0.y, a0.y);
    a0.z = fmaf(hv.z, x0.z, a0.z);
    a0.w = fmaf(hv.w, x0.w, a0.w);
    a1.x = fmaf(hv.x, x1.x, a1.x);
    a1.y = fmaf(hv.y, x1.y, a1.y);
    a1.z = fmaf(hv.z, x1.z, a1.z);
    a1.w = fmaf(hv.w, x1.w, a1.w);
  }
  float d0 = (a0.x + a0.y) + (a0.z + a0.w);
  float d1 = (a1.x + a1.y) + (a1.z + a1.w);
  ((float2*)out)[row] = make_float2(d0, d1);
}

// ---------------------------------------------------------------------------
// Launch
// ---------------------------------------------------------------------------
extern "C" void kernel_launch(void* const* d_in, const int* in_sizes, int n_in,
                              void* d_out, int out_size, void* d_ws,
                              size_t ws_size, hipStream_t stream) {
  const float* input = (const float*)d_in[0];  // [B,T,DI]
  const float* noise = (const float*)d_in[1];  // [B,T,H]
  const float* W_x = (const float*)d_in[2];    // [H,DI]
  const float* b_ah = (const float*)d_in[3];   // [H]
  const float* W_h = (const float*)d_in[4];    // [H,H]
  const float* W_y = (const float*)d_in[5];    // [DO,H]
  const float* ah0 = (const float*)d_in[6];    // [H]

  float* out = (float*)d_out;                    // [B,T,DO]
  float* hstore = out + (size_t)BB * TT * DOUT;  // [B,T,H]
  float* WxP = (float*)d_ws;                     // padded Wx [100][104]

  // K0: pack Wx into aligned padded copy (one tiny block).
  k_prep<<<1, 256, 0, stream>>>(W_x, WxP);

  // K1: input projection -> xp staged into hstore region.
  k_inproj<<<BT / 64, 128, 0, stream>>>(input, WxP, b_ah, hstore);

  // K2: barrier-free scan, one wave per batch (AGPR-resident weights).
  k_scan<<<BB, 64, 0, stream>>>(noise, W_h, ah0, hstore);

  // K3: output projection from final hstore.
  k_outproj<<<BT / 256, 256, 0, stream>>>(hstore, W_y, out);
}